// Round 4
// baseline (468.882 us; speedup 1.0000x reference)
//
#include <hip/hip_runtime.h>
#include <math.h>

#define NUM_USERS 100000
#define NUM_ITEMS 50000
#define NN 150000               // total nodes
#define EE 1200000              // total directed edges (2 * E_DIR)
#define NNP 150016              // padded node count = 293*512
#define G8_BLOCKS 4688          // ceil(NN*8/256) for 8-lane-per-node kernels

// CSR-build (bucket sort) parameters
#define NBUCKET 293             // ceil(NNP/512); NBUCKET*512 == NNP exactly
#define NB2 512                 // blocks for mlp_hist/scatter1
#define EPB 2344                // edges per block: 512*2344 = 1200128 >= EE

typedef unsigned short ushort_t;
typedef unsigned int uint_t;

__device__ __forceinline__ uint_t pack2(float lo, float hi) {   // 2x fp32 -> bf16x2 RNE
    uint_t a = __float_as_uint(lo);
    uint_t b = __float_as_uint(hi);
    a = (a + 0x7FFFu + ((a >> 16) & 1u)) >> 16;
    b = (b + 0x7FFFu + ((b >> 16) & 1u)) & 0xFFFF0000u;
    return a | b;
}
__device__ __forceinline__ float lo16(uint_t x) { return __uint_as_float(x << 16); }
__device__ __forceinline__ float hi16(uint_t x) { return __uint_as_float(x & 0xFFFF0000u); }

// ---- K1: edge MLP + per-block bucket histogram (LDS atomics only) -----------
// 512 blocks x 256 thr, each block owns edges [B*EPB, B*EPB+EPB) — the SAME
// partition scatter1 uses, so hist[bucket][block] lines up.
__global__ void mlp_hist_kernel(const float* __restrict__ feats,
                                const float* __restrict__ w1,
                                const float* __restrict__ b1,
                                const float* __restrict__ w2,
                                const float* __restrict__ b2,
                                const int* __restrict__ col,
                                float* __restrict__ wout,
                                int* __restrict__ hist,
                                int* __restrict__ done) {
    __shared__ float sw1t[256];      // transposed: sw1t[j*8+i] = w1[i][j]
    __shared__ float2 shb[32];       // {b1[j], w2[j]}
    __shared__ float sb2s;
    __shared__ int h[NBUCKET];
    int t = threadIdx.x, B = blockIdx.x;
    sw1t[t] = w1[(t & 7) * 32 + (t >> 3)];
    if (t < 32) shb[t] = make_float2(b1[t], w2[t]);
    if (t == 0) sb2s = b2[0];
    if (B == 0 && t == 0) *done = 0;          // init scanb's completion counter
    for (int i = t; i < NBUCKET; i += 256) h[i] = 0;
    __syncthreads();
    int beg = B * EPB, end = beg + EPB; if (end > EE) end = EE;
    for (int e = beg + t; e < end; e += 256) {
        atomicAdd(&h[col[e] >> 9], 1);                     // LDS atomic
        const float4* fp = (const float4*)(feats + (size_t)e * 8);
        float4 fa = fp[0], fb = fp[1];
        float f0 = fa.x, f1 = fa.y, f2 = fa.z, f3 = fa.w;
        float f4 = fb.x, f5 = fb.y, f6 = fb.z, f7 = fb.w;
        float s = sb2s;
#pragma unroll
        for (int j = 0; j < 32; ++j) {
            float4 wa = *(const float4*)&sw1t[j * 8];
            float4 wb = *(const float4*)&sw1t[j * 8 + 4];
            float2 bw = shb[j];
            float hh = bw.x;
            hh = fmaf(f0, wa.x, hh);
            hh = fmaf(f1, wa.y, hh);
            hh = fmaf(f2, wa.z, hh);
            hh = fmaf(f3, wa.w, hh);
            hh = fmaf(f4, wb.x, hh);
            hh = fmaf(f5, wb.y, hh);
            hh = fmaf(f6, wb.z, hh);
            hh = fmaf(f7, wb.w, hh);
            hh = fmaxf(hh, 0.f);
            s = fmaf(hh, bw.y, s);
        }
        wout[e] = 1.f / (1.f + expf(-s));
    }
    __syncthreads();
    for (int i = t; i < NBUCKET; i += 256) hist[i * NB2 + B] = h[i];
}

// ---- K2: per-bucket exclusive scan of 512 block-counts; last block also -----
//      scans bucket totals -> base[] (device-scope atomics for coherence)
__global__ void scanb_kernel(int* __restrict__ hist,       // [NBUCKET][NB2]
                             int* __restrict__ tot,        // [NBUCKET]
                             int* __restrict__ base,       // [NBUCKET+1]
                             int* __restrict__ done) {
    __shared__ int wsum[8];
    __shared__ int lastflag;
    int b = blockIdx.x, t = threadIdx.x;                   // 512 threads
    int v = hist[b * NB2 + t];
    int lane = t & 63;
    int s = v;
#pragma unroll
    for (int off = 1; off < 64; off <<= 1) {
        int u = __shfl_up(s, off, 64);
        if (lane >= off) s += u;
    }
    if (lane == 63) wsum[t >> 6] = s;
    __syncthreads();
    int add = 0;
    for (int w = 0; w < (t >> 6); ++w) add += wsum[w];
    hist[b * NB2 + t] = s - v + add;                       // exclusive prefix
    if (t == 511) atomicExch(&tot[b], s + add);            // bucket total (coherent)
    __syncthreads();                                       // drains the exch (vmcnt0)
    if (t == 0) lastflag = (atomicAdd(done, 1) == NBUCKET - 1);
    __syncthreads();
    if (lastflag) {                                        // one block scans totals
        int v2 = (t < NBUCKET) ? atomicOr(&tot[t], 0) : 0; // coherent read
        int s2 = v2;
#pragma unroll
        for (int off = 1; off < 64; off <<= 1) {
            int u = __shfl_up(s2, off, 64);
            if (lane >= off) s2 += u;
        }
        if (lane == 63) wsum[t >> 6] = s2;
        __syncthreads();
        int add2 = 0;
        for (int w = 0; w < (t >> 6); ++w) add2 += wsum[w];
        if (t < NBUCKET) base[t] = s2 - v2 + add2;         // exclusive
        if (t == 511) base[NBUCKET] = s2 + add2;           // == EE
    }
}

// ---- K3: scatter edges into bucket-major tmp records (L2-local runs) --------
// tmp record int2: {(row<<9)|(col&511), w_bits} — row<2^18, col_lo 9b
__global__ void scatter1_kernel(const int* __restrict__ col,
                                const int* __restrict__ row,
                                const float* __restrict__ wbuf,
                                const int* __restrict__ hist,   // scanned
                                const int* __restrict__ base,
                                int2* __restrict__ tmp) {
    __shared__ int bbase[NBUCKET];
    __shared__ int cur[NBUCKET];
    int t = threadIdx.x, B = blockIdx.x;
    for (int i = t; i < NBUCKET; i += 256) {
        bbase[i] = base[i] + hist[i * NB2 + B];
        cur[i] = 0;
    }
    __syncthreads();
    int beg = B * EPB, end = beg + EPB; if (end > EE) end = EE;
    for (int i = beg + t; i < end; i += 256) {
        int c = col[i];
        int b = c >> 9;
        int r = atomicAdd(&cur[b], 1);                     // LDS returning atomic
        tmp[bbase[b] + r] = make_int2((row[i] << 9) | (c & 511),
                                      __float_as_int(wbuf[i]));
    }
}

// ---- K4: within-bucket exact-col sort -> packed + offs + degree/dinv --------
__global__ void scatter2_kernel(const int2* __restrict__ tmp,
                                const int* __restrict__ base,
                                int* __restrict__ offs,
                                int2* __restrict__ packed,
                                float* __restrict__ dinv) {
    __shared__ int sc[512];                                // count -> scan -> cursor
    __shared__ float sdeg[512];                            // per-col sum of w
    __shared__ int wsum[8];
    int b = blockIdx.x, t = threadIdx.x;                   // 512 threads
    int beg = base[b], end = base[b + 1];
    sc[t] = 0;
    sdeg[t] = 0.f;
    __syncthreads();
    for (int i = beg + t; i < end; i += 512) {
        int2 rec = tmp[i];
        int cl = rec.x & 511;
        atomicAdd(&sc[cl], 1);                             // per-col count (LDS)
        atomicAdd(&sdeg[cl], __int_as_float(rec.y));       // per-col degree (LDS f32)
    }
    __syncthreads();
    int v = sc[t];
    int lane = t & 63;
    int s = v;
#pragma unroll
    for (int off = 1; off < 64; off <<= 1) {
        int u = __shfl_up(s, off, 64);
        if (lane >= off) s += u;
    }
    if (lane == 63) wsum[t >> 6] = s;
    __syncthreads();
    int add = 0;
    for (int w = 0; w < (t >> 6); ++w) add += wsum[w];
    int excl = s - v + add;
    offs[b * 512 + t] = beg + excl;                        // global CSR offset
    int g = b * 512 + t;
    if (g < NN) {
        float ds = sdeg[t];
        dinv[g] = (ds > 0.f) ? rsqrtf(ds) : 0.f;
    }
    __syncthreads();
    sc[t] = excl;                                          // becomes cursor
    __syncthreads();
    for (int i = beg + t; i < end; i += 512) {
        int2 rec = tmp[i];
        int r = atomicAdd(&sc[rec.x & 511], 1);            // within-bucket slot
        packed[beg + r] = make_int2(((uint_t)rec.x) >> 9, rec.y);
    }
}

// ---- gather core: 8 lanes per node, 16B loads; a0/a1 = cols 8c..8c+7 --------
__device__ __forceinline__ void gather_node8(const ushort_t* __restrict__ zin,
                                             const int2* __restrict__ packed,
                                             int beg, int end, unsigned c,
                                             float4& a0, float4& a1) {
    for (int base = beg; base < end; base += 8) {
        int m = end - base; if (m > 8) m = 8;
        int r = 0; float w = 0.f;
        if ((int)c < m) {
            int2 p = packed[base + (int)c];
            r = p.x; w = __int_as_float(p.y);
        }
        int rj[8]; float wj[8]; uint4 vj[8];
#pragma unroll
        for (int u = 0; u < 8; ++u) {
            int idx = (u < m) ? u : (m - 1);       // clamp: re-read last valid row
            rj[u] = __shfl(r, idx, 8);
            wj[u] = __shfl(w, u, 8);               // lanes >= m carry w=0
        }
#pragma unroll
        for (int u = 0; u < 8; ++u)
            vj[u] = *(const uint4*)(zin + (size_t)(uint_t)rj[u] * 64u + c * 8u);
#pragma unroll
        for (int u = 0; u < 8; ++u) {
            float ww = wj[u]; uint4 v = vj[u];
            a0.x = fmaf(ww, lo16(v.x), a0.x);
            a0.y = fmaf(ww, hi16(v.x), a0.y);
            a0.z = fmaf(ww, lo16(v.y), a0.z);
            a0.w = fmaf(ww, hi16(v.y), a0.w);
            a1.x = fmaf(ww, lo16(v.z), a1.x);
            a1.y = fmaf(ww, hi16(v.z), a1.y);
            a1.z = fmaf(ww, lo16(v.w), a1.z);
            a1.w = fmaf(ww, hi16(v.w), a1.w);
        }
    }
}

// ---- z0 init (8 lanes per node); dinv precomputed by scatter2 ---------------
__global__ void dinv_init_kernel(const int* __restrict__ offs,
                                 const float* __restrict__ user_w,
                                 const float* __restrict__ audio,
                                 const float* __restrict__ artist_w,
                                 const float* __restrict__ album_w,
                                 const int* __restrict__ artist_ids,
                                 const int* __restrict__ album_ids,
                                 const float* __restrict__ dinv,
                                 ushort_t* __restrict__ z0) {
    unsigned t = blockIdx.x * 256u + threadIdx.x;
    unsigned node = t >> 3, c = t & 7u;
    if (node >= NN) return;
    float d = dinv[node];

    size_t ri = (size_t)node * 64u + c * 8u;
    float v[8];
    if (node < NUM_USERS) {
        float4 x0 = *(const float4*)(user_w + ri);
        float4 x1 = *(const float4*)(user_w + ri + 4);
        v[0]=x0.x; v[1]=x0.y; v[2]=x0.z; v[3]=x0.w;
        v[4]=x1.x; v[5]=x1.y; v[6]=x1.z; v[7]=x1.w;
    } else {
        unsigned j = node - NUM_USERS;
        unsigned aid = (unsigned)artist_ids[j], bid = (unsigned)album_ids[j];
        const float* ap = artist_w + (size_t)aid * 64u + c * 8u;
        const float* bp = album_w  + (size_t)bid * 64u + c * 8u;
        const float* up = audio    + (size_t)j   * 64u + c * 8u;
        float4 A0 = *(const float4*)ap, A1 = *(const float4*)(ap + 4);
        float4 B0 = *(const float4*)bp, B1 = *(const float4*)(bp + 4);
        float4 U0 = *(const float4*)up, U1 = *(const float4*)(up + 4);
        v[0] = fmaf(0.44f, A0.x + B0.x, 0.3f * U0.x);
        v[1] = fmaf(0.44f, A0.y + B0.y, 0.3f * U0.y);
        v[2] = fmaf(0.44f, A0.z + B0.z, 0.3f * U0.z);
        v[3] = fmaf(0.44f, A0.w + B0.w, 0.3f * U0.w);
        v[4] = fmaf(0.44f, A1.x + B1.x, 0.3f * U1.x);
        v[5] = fmaf(0.44f, A1.y + B1.y, 0.3f * U1.y);
        v[6] = fmaf(0.44f, A1.z + B1.z, 0.3f * U1.z);
        v[7] = fmaf(0.44f, A1.w + B1.w, 0.3f * U1.w);
    }
    float s = 0.f;
#pragma unroll
    for (int k = 0; k < 8; ++k) s = fmaf(v[k], v[k], s);
    s += __shfl_xor(s, 1, 8);
    s += __shfl_xor(s, 2, 8);
    s += __shfl_xor(s, 4, 8);
    float rn = rsqrtf(fmaxf(s, 1e-24f));          // == 1/max(||x||,1e-12)
    float scale = ((d > 0.f) ? d : 1.f) * rn;
    uint4 o;
    o.x = pack2(v[0] * scale, v[1] * scale);
    o.y = pack2(v[2] * scale, v[3] * scale);
    o.z = pack2(v[4] * scale, v[5] * scale);
    o.w = pack2(v[6] * scale, v[7] * scale);
    *(uint4*)(z0 + ri) = o;
}

// ---- SpMM layer in z-space: zout[n] = dinv_n^2 * sum ew * zin[row] ----------
__global__ void spmm_kernel(const ushort_t* __restrict__ zin,
                            const int2* __restrict__ packed,
                            const int* __restrict__ offs,
                            const float* __restrict__ dinv,
                            ushort_t* __restrict__ zout) {
    unsigned t = blockIdx.x * 256u + threadIdx.x;
    unsigned node = t >> 3, c = t & 7u;
    if (node >= NN) return;
    float4 a0 = make_float4(0,0,0,0), a1 = make_float4(0,0,0,0);
    gather_node8(zin, packed, offs[node], offs[node + 1], c, a0, a1);
    float d = dinv[node], dd = d * d;
    uint4 o;
    o.x = pack2(a0.x * dd, a0.y * dd);
    o.y = pack2(a0.z * dd, a0.w * dd);
    o.z = pack2(a1.x * dd, a1.y * dd);
    o.w = pack2(a1.z * dd, a1.w * dd);
    *(uint4*)(zout + (size_t)node * 64u + c * 8u) = o;
}

// ---- final layer fused with l2norm: out = l2norm((z0+z1+z2+z3)/4) -----------
__global__ void spmm_final_kernel(const ushort_t* __restrict__ z0,
                                  const ushort_t* __restrict__ z1,
                                  const ushort_t* __restrict__ z2,
                                  const int2* __restrict__ packed,
                                  const int* __restrict__ offs,
                                  const float* __restrict__ dinv,
                                  float* __restrict__ out) {
    unsigned t = blockIdx.x * 256u + threadIdx.x;
    unsigned node = t >> 3, c = t & 7u;
    if (node >= NN) return;
    float4 a0 = make_float4(0,0,0,0), a1 = make_float4(0,0,0,0);
    gather_node8(z2, packed, offs[node], offs[node + 1], c, a0, a1);
    float d = dinv[node], dd = d * d;
    size_t ri = (size_t)node * 64u + c * 8u;
    uint4 p0 = *(const uint4*)(z0 + ri);
    uint4 p1 = *(const uint4*)(z1 + ri);
    uint4 p2 = *(const uint4*)(z2 + ri);
    float v[8];
    v[0] = lo16(p0.x) + lo16(p1.x) + lo16(p2.x) + a0.x * dd;
    v[1] = hi16(p0.x) + hi16(p1.x) + hi16(p2.x) + a0.y * dd;
    v[2] = lo16(p0.y) + lo16(p1.y) + lo16(p2.y) + a0.z * dd;
    v[3] = hi16(p0.y) + hi16(p1.y) + hi16(p2.y) + a0.w * dd;
    v[4] = lo16(p0.z) + lo16(p1.z) + lo16(p2.z) + a1.x * dd;
    v[5] = hi16(p0.z) + hi16(p1.z) + hi16(p2.z) + a1.y * dd;
    v[6] = lo16(p0.w) + lo16(p1.w) + lo16(p2.w) + a1.z * dd;
    v[7] = hi16(p0.w) + hi16(p1.w) + hi16(p2.w) + a1.w * dd;
    float s = 0.f;
#pragma unroll
    for (int k = 0; k < 8; ++k) s = fmaf(v[k], v[k], s);
    s += __shfl_xor(s, 1, 8);
    s += __shfl_xor(s, 2, 8);
    s += __shfl_xor(s, 4, 8);
    float n = fmaxf(sqrtf(s) * 0.25f, 1e-12f);    // norm of acc/4, ref eps
    float inv = 0.25f / n;
    float4 o0 = make_float4(v[0]*inv, v[1]*inv, v[2]*inv, v[3]*inv);
    float4 o1 = make_float4(v[4]*inv, v[5]*inv, v[6]*inv, v[7]*inv);
    *(float4*)(out + ri)     = o0;
    *(float4*)(out + ri + 4) = o1;
    if (t == 0) out[(size_t)NN * 64u] = 0.f;      // align_loss
}

extern "C" void kernel_launch(void* const* d_in, const int* in_sizes, int n_in,
                              void* d_out, int out_size, void* d_ws, size_t ws_size,
                              hipStream_t stream) {
    const float* user_w     = (const float*)d_in[0];
    const float* audio      = (const float*)d_in[1];
    const float* artist_w   = (const float*)d_in[2];
    const float* album_w    = (const float*)d_in[3];
    const float* w1         = (const float*)d_in[4];
    const float* b1         = (const float*)d_in[5];
    const float* w2         = (const float*)d_in[6];
    const float* b2         = (const float*)d_in[7];
    const float* feats      = (const float*)d_in[8];
    const int*   row        = (const int*)d_in[9];
    const int*   col        = row + EE;
    const int*   artist_ids = (const int*)d_in[10];
    const int*   album_ids  = (const int*)d_in[11];
    float* out = (float*)d_out;

    // workspace (4B units):
    //   hist[NBUCKET*NB2] tot[512] base[512] done[16] offs[NNP+16]
    //   wbuf[EE] dinv[NN] packed[EE int2] z0 z1 z2 (bf16 rows)
    //   tmp (int2[EE], 9.6MB) aliased onto z1 (dead before spmm #1 writes z1)
    int*      hist    = (int*)d_ws;
    int*      tot     = hist + NBUCKET * NB2;
    int*      base    = tot + 512;
    int*      done    = base + 512;
    int*      offs    = done + 16;
    float*    wbuf    = (float*)(offs + NNP + 16);
    float*    dinv    = wbuf + EE;
    int2*     packed  = (int2*)(dinv + NN);
    ushort_t* z0      = (ushort_t*)(packed + EE);
    ushort_t* z1      = z0 + (size_t)NN * 64;
    ushort_t* z2      = z1 + (size_t)NN * 64;
    int2*     tmp     = (int2*)z1;

    mlp_hist_kernel<<<NB2, 256, 0, stream>>>(feats, w1, b1, w2, b2, col,
                                             wbuf, hist, done);
    scanb_kernel<<<NBUCKET, 512, 0, stream>>>(hist, tot, base, done);
    scatter1_kernel<<<NB2, 256, 0, stream>>>(col, row, wbuf, hist, base, tmp);
    scatter2_kernel<<<NBUCKET, 512, 0, stream>>>(tmp, base, offs, packed, dinv);
    dinv_init_kernel<<<G8_BLOCKS, 256, 0, stream>>>(offs,
                                                    user_w, audio, artist_w, album_w,
                                                    artist_ids, album_ids, dinv, z0);
    spmm_kernel<<<G8_BLOCKS, 256, 0, stream>>>(z0, packed, offs, dinv, z1);
    spmm_kernel<<<G8_BLOCKS, 256, 0, stream>>>(z1, packed, offs, dinv, z2);
    spmm_final_kernel<<<G8_BLOCKS, 256, 0, stream>>>(z0, z1, z2, packed, offs,
                                                     dinv, out);
}

// Round 6
// 301.982 us; speedup vs baseline: 1.5527x; 1.5527x over previous
//
#include <hip/hip_runtime.h>
#include <math.h>

#define NUM_USERS 100000
#define NUM_ITEMS 50000
#define NN 150000               // total nodes
#define EE 1200000              // total directed edges (2 * E_DIR)
#define NNP 150016              // padded node count = 293*512
#define G8_BLOCKS 4688          // ceil(NN*8/256) for 8-lane-per-node kernels

// CSR-build (bucket sort) parameters — round-3 measured-good config
#define NBUCKET 293             // ceil(NNP/512); NBUCKET*512 == NNP exactly
#define NB2 256                 // blocks for hist/scatter1
#define EPB 4688                // edges per block = ceil(EE/NB2)

typedef unsigned short ushort_t;
typedef unsigned int uint_t;

__device__ __forceinline__ uint_t pack2(float lo, float hi) {   // 2x fp32 -> bf16x2 RNE
    uint_t a = __float_as_uint(lo);
    uint_t b = __float_as_uint(hi);
    a = (a + 0x7FFFu + ((a >> 16) & 1u)) >> 16;
    b = (b + 0x7FFFu + ((b >> 16) & 1u)) & 0xFFFF0000u;
    return a | b;
}
__device__ __forceinline__ float lo16(uint_t x) { return __uint_as_float(x << 16); }
__device__ __forceinline__ float hi16(uint_t x) { return __uint_as_float(x & 0xFFFF0000u); }

// ---- edge MLP only: w[e] = sigmoid(mlp(feats[e])).  1 edge/thread. ----------
// NOTE (r1,r4): do NOT batch edges per thread or fuse histograms here — both
// restructures amplified memory traffic 12-15x. This exact shape measures fast.
__global__ void mlp_kernel(const float* __restrict__ feats,
                           const float* __restrict__ w1,
                           const float* __restrict__ b1,
                           const float* __restrict__ w2,
                           const float* __restrict__ b2,
                           float* __restrict__ wout) {
    __shared__ float sw1t[256];      // transposed: sw1t[j*8+i] = w1[i][j]
    __shared__ float2 shb[32];       // {b1[j], w2[j]}
    __shared__ float sb2s;
    int t = threadIdx.x;
    sw1t[t] = w1[(t & 7) * 32 + (t >> 3)];
    if (t < 32) shb[t] = make_float2(b1[t], w2[t]);
    if (t == 0) sb2s = b2[0];
    __syncthreads();
    int e = blockIdx.x * 256 + t;
    if (e >= EE) return;
    const float4* fp = (const float4*)(feats + (size_t)e * 8);
    float4 fa = fp[0], fb = fp[1];
    float f[8] = {fa.x, fa.y, fa.z, fa.w, fb.x, fb.y, fb.z, fb.w};
    float s = sb2s;
#pragma unroll
    for (int j = 0; j < 32; ++j) {
        float4 wa = *(const float4*)&sw1t[j * 8];
        float4 wb = *(const float4*)&sw1t[j * 8 + 4];
        float2 bw = shb[j];
        float h = bw.x;
        h = fmaf(f[0], wa.x, h);
        h = fmaf(f[1], wa.y, h);
        h = fmaf(f[2], wa.z, h);
        h = fmaf(f[3], wa.w, h);
        h = fmaf(f[4], wb.x, h);
        h = fmaf(f[5], wb.y, h);
        h = fmaf(f[6], wb.z, h);
        h = fmaf(f[7], wb.w, h);
        h = fmaxf(h, 0.f);
        s = fmaf(h, bw.y, s);
    }
    wout[e] = 1.f / (1.f + expf(-s));
}

// ---- K2: per-block bucket histogram (bucket = col>>9), LDS atomics only -----
__global__ void hist_kernel(const int* __restrict__ col,
                            int* __restrict__ hist) {      // hist[NBUCKET*NB2]
    __shared__ int h[NBUCKET];
    int t = threadIdx.x, B = blockIdx.x;
    for (int i = t; i < NBUCKET; i += 256) h[i] = 0;
    __syncthreads();
    int beg = B * EPB, end = beg + EPB; if (end > EE) end = EE;
    for (int i = beg + t; i < end; i += 256)
        atomicAdd(&h[col[i] >> 9], 1);                     // LDS atomic
    __syncthreads();
    for (int i = t; i < NBUCKET; i += 256) hist[i * NB2 + B] = h[i];
}

// ---- K3: per-bucket exclusive scan over its 256 block-counts (in place) -----
__global__ void scanb_kernel(int* __restrict__ hist,       // [NBUCKET][NB2]
                             int* __restrict__ tot) {      // [NBUCKET]
    int b = blockIdx.x, t = threadIdx.x;
    int v = hist[b * NB2 + t];
    int lane = t & 63;
    int s = v;
#pragma unroll
    for (int off = 1; off < 64; off <<= 1) {
        int u = __shfl_up(s, off, 64);
        if (lane >= off) s += u;
    }
    __shared__ int wsum[4];
    if (lane == 63) wsum[t >> 6] = s;
    __syncthreads();
    int add = 0;
    for (int w = 0; w < (t >> 6); ++w) add += wsum[w];
    hist[b * NB2 + t] = s - v + add;                       // exclusive prefix
    if (t == 255) tot[b] = s + add;                        // bucket total
}

// ---- K3b: scan bucket totals -> bucket base offsets (single block) ----------
__global__ void scant_kernel(const int* __restrict__ tot,
                             int* __restrict__ base) {     // base[NBUCKET+1]
    int t = threadIdx.x;                                   // 512 threads
    int v = (t < NBUCKET) ? tot[t] : 0;
    int lane = t & 63;
    int s = v;
#pragma unroll
    for (int off = 1; off < 64; off <<= 1) {
        int u = __shfl_up(s, off, 64);
        if (lane >= off) s += u;
    }
    __shared__ int wsum[8];
    if (lane == 63) wsum[t >> 6] = s;
    __syncthreads();
    int add = 0;
    for (int w = 0; w < (t >> 6); ++w) add += wsum[w];
    if (t < NBUCKET) base[t] = s - v + add;                // exclusive
    if (t == 511) base[NBUCKET] = s + add;                 // == EE
}

// ---- K4: scatter edges into bucket-major tmp records (L2-local runs) --------
// tmp record int2: {(row<<9)|(col&511), w_bits} — row<2^18, col_lo 9b
__global__ void scatter1_kernel(const int* __restrict__ col,
                                const int* __restrict__ row,
                                const float* __restrict__ wbuf,
                                const int* __restrict__ hist,   // scanned
                                const int* __restrict__ base,
                                int2* __restrict__ tmp) {
    __shared__ int bbase[NBUCKET];
    __shared__ int cur[NBUCKET];
    int t = threadIdx.x, B = blockIdx.x;
    for (int i = t; i < NBUCKET; i += 256) {
        bbase[i] = base[i] + hist[i * NB2 + B];
        cur[i] = 0;
    }
    __syncthreads();
    int beg = B * EPB, end = beg + EPB; if (end > EE) end = EE;
    for (int i = beg + t; i < end; i += 256) {
        int c = col[i];
        int b = c >> 9;
        int r = atomicAdd(&cur[b], 1);                     // LDS returning atomic
        tmp[bbase[b] + r] = make_int2((row[i] << 9) | (c & 511),
                                      __float_as_int(wbuf[i]));
    }
}

// ---- K5: within-bucket exact-col sort -> packed + offs + degree/dinv --------
__global__ void scatter2_kernel(const int2* __restrict__ tmp,
                                const int* __restrict__ base,
                                int* __restrict__ offs,
                                int2* __restrict__ packed,
                                float* __restrict__ dinv) {
    __shared__ int sc[512];                                // count -> scan -> cursor
    __shared__ float sdeg[512];                            // per-col sum of w
    __shared__ int wsum[8];
    int b = blockIdx.x, t = threadIdx.x;                   // 512 threads
    int beg = base[b], end = base[b + 1];
    sc[t] = 0;
    sdeg[t] = 0.f;
    __syncthreads();
    for (int i = beg + t; i < end; i += 512) {
        int2 rec = tmp[i];
        int cl = rec.x & 511;
        atomicAdd(&sc[cl], 1);                             // per-col count (LDS)
        atomicAdd(&sdeg[cl], __int_as_float(rec.y));       // per-col degree (LDS f32)
    }
    __syncthreads();
    int v = sc[t];
    int lane = t & 63;
    int s = v;
#pragma unroll
    for (int off = 1; off < 64; off <<= 1) {
        int u = __shfl_up(s, off, 64);
        if (lane >= off) s += u;
    }
    if (lane == 63) wsum[t >> 6] = s;
    __syncthreads();
    int add = 0;
    for (int w = 0; w < (t >> 6); ++w) add += wsum[w];
    int excl = s - v + add;
    offs[b * 512 + t] = beg + excl;                        // global CSR offset
    int g = b * 512 + t;
    if (g < NN) {
        float ds = sdeg[t];
        dinv[g] = (ds > 0.f) ? rsqrtf(ds) : 0.f;
    }
    __syncthreads();
    sc[t] = excl;                                          // becomes cursor
    __syncthreads();
    for (int i = beg + t; i < end; i += 512) {
        int2 rec = tmp[i];
        int r = atomicAdd(&sc[rec.x & 511], 1);            // within-bucket slot
        packed[beg + r] = make_int2(((uint_t)rec.x) >> 9, rec.y);
    }
}

// ---- gather core: 8 lanes per node, 16B loads; a0/a1 = cols 8c..8c+7 --------
__device__ __forceinline__ void gather_node8(const ushort_t* __restrict__ zin,
                                             const int2* __restrict__ packed,
                                             int beg, int end, unsigned c,
                                             float4& a0, float4& a1) {
    for (int base = beg; base < end; base += 8) {
        int m = end - base; if (m > 8) m = 8;
        int r = 0; float w = 0.f;
        if ((int)c < m) {
            int2 p = packed[base + (int)c];
            r = p.x; w = __int_as_float(p.y);
        }
        int rj[8]; float wj[8]; uint4 vj[8];
#pragma unroll
        for (int u = 0; u < 8; ++u) {
            int idx = (u < m) ? u : (m - 1);       // clamp: re-read last valid row
            rj[u] = __shfl(r, idx, 8);
            wj[u] = __shfl(w, u, 8);               // lanes >= m carry w=0
        }
#pragma unroll
        for (int u = 0; u < 8; ++u)
            vj[u] = *(const uint4*)(zin + (size_t)(uint_t)rj[u] * 64u + c * 8u);
#pragma unroll
        for (int u = 0; u < 8; ++u) {
            float ww = wj[u]; uint4 v = vj[u];
            a0.x = fmaf(ww, lo16(v.x), a0.x);
            a0.y = fmaf(ww, hi16(v.x), a0.y);
            a0.z = fmaf(ww, lo16(v.y), a0.z);
            a0.w = fmaf(ww, hi16(v.y), a0.w);
            a1.x = fmaf(ww, lo16(v.z), a1.x);
            a1.y = fmaf(ww, hi16(v.z), a1.y);
            a1.z = fmaf(ww, lo16(v.w), a1.z);
            a1.w = fmaf(ww, hi16(v.w), a1.w);
        }
    }
}

// ---- z0 init (8 lanes per node); dinv precomputed by scatter2 ---------------
__global__ void dinv_init_kernel(const int* __restrict__ offs,
                                 const float* __restrict__ user_w,
                                 const float* __restrict__ audio,
                                 const float* __restrict__ artist_w,
                                 const float* __restrict__ album_w,
                                 const int* __restrict__ artist_ids,
                                 const int* __restrict__ album_ids,
                                 const float* __restrict__ dinv,
                                 ushort_t* __restrict__ z0) {
    unsigned t = blockIdx.x * 256u + threadIdx.x;
    unsigned node = t >> 3, c = t & 7u;
    if (node >= NN) return;
    float d = dinv[node];

    size_t ri = (size_t)node * 64u + c * 8u;
    float v[8];
    if (node < NUM_USERS) {
        float4 x0 = *(const float4*)(user_w + ri);
        float4 x1 = *(const float4*)(user_w + ri + 4);
        v[0]=x0.x; v[1]=x0.y; v[2]=x0.z; v[3]=x0.w;
        v[4]=x1.x; v[5]=x1.y; v[6]=x1.z; v[7]=x1.w;
    } else {
        unsigned j = node - NUM_USERS;
        unsigned aid = (unsigned)artist_ids[j], bid = (unsigned)album_ids[j];
        const float* ap = artist_w + (size_t)aid * 64u + c * 8u;
        const float* bp = album_w  + (size_t)bid * 64u + c * 8u;
        const float* up = audio    + (size_t)j   * 64u + c * 8u;
        float4 A0 = *(const float4*)ap, A1 = *(const float4*)(ap + 4);
        float4 B0 = *(const float4*)bp, B1 = *(const float4*)(bp + 4);
        float4 U0 = *(const float4*)up, U1 = *(const float4*)(up + 4);
        v[0] = fmaf(0.44f, A0.x + B0.x, 0.3f * U0.x);
        v[1] = fmaf(0.44f, A0.y + B0.y, 0.3f * U0.y);
        v[2] = fmaf(0.44f, A0.z + B0.z, 0.3f * U0.z);
        v[3] = fmaf(0.44f, A0.w + B0.w, 0.3f * U0.w);
        v[4] = fmaf(0.44f, A1.x + B1.x, 0.3f * U1.x);
        v[5] = fmaf(0.44f, A1.y + B1.y, 0.3f * U1.y);
        v[6] = fmaf(0.44f, A1.z + B1.z, 0.3f * U1.z);
        v[7] = fmaf(0.44f, A1.w + B1.w, 0.3f * U1.w);
    }
    float s = 0.f;
#pragma unroll
    for (int k = 0; k < 8; ++k) s = fmaf(v[k], v[k], s);
    s += __shfl_xor(s, 1, 8);
    s += __shfl_xor(s, 2, 8);
    s += __shfl_xor(s, 4, 8);
    float rn = rsqrtf(fmaxf(s, 1e-24f));          // == 1/max(||x||,1e-12)
    float scale = ((d > 0.f) ? d : 1.f) * rn;
    uint4 o;
    o.x = pack2(v[0] * scale, v[1] * scale);
    o.y = pack2(v[2] * scale, v[3] * scale);
    o.z = pack2(v[4] * scale, v[5] * scale);
    o.w = pack2(v[6] * scale, v[7] * scale);
    *(uint4*)(z0 + ri) = o;
}

// ---- SpMM layer in z-space: zout[n] = dinv_n^2 * sum ew * zin[row] ----------
__global__ void spmm_kernel(const ushort_t* __restrict__ zin,
                            const int2* __restrict__ packed,
                            const int* __restrict__ offs,
                            const float* __restrict__ dinv,
                            ushort_t* __restrict__ zout) {
    unsigned t = blockIdx.x * 256u + threadIdx.x;
    unsigned node = t >> 3, c = t & 7u;
    if (node >= NN) return;
    float4 a0 = make_float4(0,0,0,0), a1 = make_float4(0,0,0,0);
    gather_node8(zin, packed, offs[node], offs[node + 1], c, a0, a1);
    float d = dinv[node], dd = d * d;
    uint4 o;
    o.x = pack2(a0.x * dd, a0.y * dd);
    o.y = pack2(a0.z * dd, a0.w * dd);
    o.z = pack2(a1.x * dd, a1.y * dd);
    o.w = pack2(a1.z * dd, a1.w * dd);
    *(uint4*)(zout + (size_t)node * 64u + c * 8u) = o;
}

// ---- final layer fused with l2norm: out = l2norm((z0+z1+z2+z3)/4) -----------
__global__ void spmm_final_kernel(const ushort_t* __restrict__ z0,
                                  const ushort_t* __restrict__ z1,
                                  const ushort_t* __restrict__ z2,
                                  const int2* __restrict__ packed,
                                  const int* __restrict__ offs,
                                  const float* __restrict__ dinv,
                                  float* __restrict__ out) {
    unsigned t = blockIdx.x * 256u + threadIdx.x;
    unsigned node = t >> 3, c = t & 7u;
    if (node >= NN) return;
    float4 a0 = make_float4(0,0,0,0), a1 = make_float4(0,0,0,0);
    gather_node8(z2, packed, offs[node], offs[node + 1], c, a0, a1);
    float d = dinv[node], dd = d * d;
    size_t ri = (size_t)node * 64u + c * 8u;
    uint4 p0 = *(const uint4*)(z0 + ri);
    uint4 p1 = *(const uint4*)(z1 + ri);
    uint4 p2 = *(const uint4*)(z2 + ri);
    float v[8];
    v[0] = lo16(p0.x) + lo16(p1.x) + lo16(p2.x) + a0.x * dd;
    v[1] = hi16(p0.x) + hi16(p1.x) + hi16(p2.x) + a0.y * dd;
    v[2] = lo16(p0.y) + lo16(p1.y) + lo16(p2.y) + a0.z * dd;
    v[3] = hi16(p0.y) + hi16(p1.y) + hi16(p2.y) + a0.w * dd;
    v[4] = lo16(p0.z) + lo16(p1.z) + lo16(p2.z) + a1.x * dd;
    v[5] = hi16(p0.z) + hi16(p1.z) + hi16(p2.z) + a1.y * dd;
    v[6] = lo16(p0.w) + lo16(p1.w) + lo16(p2.w) + a1.z * dd;
    v[7] = hi16(p0.w) + hi16(p1.w) + hi16(p2.w) + a1.w * dd;
    float s = 0.f;
#pragma unroll
    for (int k = 0; k < 8; ++k) s = fmaf(v[k], v[k], s);
    s += __shfl_xor(s, 1, 8);
    s += __shfl_xor(s, 2, 8);
    s += __shfl_xor(s, 4, 8);
    float n = fmaxf(sqrtf(s) * 0.25f, 1e-12f);    // norm of acc/4, ref eps
    float inv = 0.25f / n;
    float4 o0 = make_float4(v[0]*inv, v[1]*inv, v[2]*inv, v[3]*inv);
    float4 o1 = make_float4(v[4]*inv, v[5]*inv, v[6]*inv, v[7]*inv);
    *(float4*)(out + ri)     = o0;
    *(float4*)(out + ri + 4) = o1;
    if (t == 0) out[(size_t)NN * 64u] = 0.f;      // align_loss
}

extern "C" void kernel_launch(void* const* d_in, const int* in_sizes, int n_in,
                              void* d_out, int out_size, void* d_ws, size_t ws_size,
                              hipStream_t stream) {
    const float* user_w     = (const float*)d_in[0];
    const float* audio      = (const float*)d_in[1];
    const float* artist_w   = (const float*)d_in[2];
    const float* album_w    = (const float*)d_in[3];
    const float* w1         = (const float*)d_in[4];
    const float* b1         = (const float*)d_in[5];
    const float* w2         = (const float*)d_in[6];
    const float* b2         = (const float*)d_in[7];
    const float* feats      = (const float*)d_in[8];
    const int*   row        = (const int*)d_in[9];
    const int*   col        = row + EE;
    const int*   artist_ids = (const int*)d_in[10];
    const int*   album_ids  = (const int*)d_in[11];
    float* out = (float*)d_out;

    // workspace (4B units):
    //   hist[NBUCKET*NB2] tot[512] base[512] offs[NNP+16]
    //   wbuf[EE] dinv[NN] packed[EE int2] z0 z1 z2 (bf16 rows)
    //   tmp (int2[EE], 9.6MB) aliased onto z1 (dead before spmm #1 writes z1)
    int*      hist    = (int*)d_ws;
    int*      tot     = hist + NBUCKET * NB2;
    int*      base    = tot + 512;
    int*      offs    = base + 512;
    float*    wbuf    = (float*)(offs + NNP + 16);
    float*    dinv    = wbuf + EE;
    int2*     packed  = (int2*)(dinv + NN);
    ushort_t* z0      = (ushort_t*)(packed + EE);
    ushort_t* z1      = z0 + (size_t)NN * 64;
    ushort_t* z2      = z1 + (size_t)NN * 64;
    int2*     tmp     = (int2*)z1;

    mlp_kernel<<<(EE + 255) / 256, 256, 0, stream>>>(feats, w1, b1, w2, b2, wbuf);
    hist_kernel<<<NB2, 256, 0, stream>>>(col, hist);
    scanb_kernel<<<NBUCKET, 256, 0, stream>>>(hist, tot);
    scant_kernel<<<1, 512, 0, stream>>>(tot, base);
    scatter1_kernel<<<NB2, 256, 0, stream>>>(col, row, wbuf, hist, base, tmp);
    scatter2_kernel<<<NBUCKET, 512, 0, stream>>>(tmp, base, offs, packed, dinv);
    dinv_init_kernel<<<G8_BLOCKS, 256, 0, stream>>>(offs,
                                                    user_w, audio, artist_w, album_w,
                                                    artist_ids, album_ids, dinv, z0);
    spmm_kernel<<<G8_BLOCKS, 256, 0, stream>>>(z0, packed, offs, dinv, z1);
    spmm_kernel<<<G8_BLOCKS, 256, 0, stream>>>(z1, packed, offs, dinv, z2);
    spmm_final_kernel<<<G8_BLOCKS, 256, 0, stream>>>(z0, z1, z2, packed, offs,
                                                     dinv, out);
}